// Round 10
// baseline (210.646 us; speedup 1.0000x reference)
//
#include <hip/hip_runtime.h>

#define HW    3136
#define CIN   64
#define MIDC  32
#define HEADS 8
#define DTOT  256
#define COUTC 64
#define WDIM  56
#define QT    32
#define L2E   1.4426950408889634f

typedef unsigned int uint_t;
typedef _Float16 f16;
typedef __attribute__((ext_vector_type(8))) _Float16 half8;
typedef __attribute__((ext_vector_type(2))) __fp16  fp16x2;
typedef __attribute__((ext_vector_type(4))) float f32x4;

union HU { fp16x2 h; uint_t u; };
__device__ __forceinline__ uint_t pkh(float a, float b) {
    HU u; u.h = __builtin_amdgcn_cvt_pkrtz(a, b); return u.u;
}

// ---------------- Kernel 1: fused QKV conv + layout (fp32 in -> f16 ws) ------
__global__ __launch_bounds__(256) void qkv_fused_kernel(
    const float* __restrict__ x,
    const float* __restrict__ Wq, const float* __restrict__ bq,
    const float* __restrict__ Wk, const float* __restrict__ bk,
    const float* __restrict__ Wv, const float* __restrict__ bv,
    f16* __restrict__ qh, f16* __restrict__ kh, f16* __restrict__ vh)
{
    __shared__ float xs[64][36];
    __shared__ float Wlq[64][34];
    __shared__ float Wlk[64][34];
    __shared__ float Wlv[64][34];

    const int tid = threadIdx.x;
    const int h   = blockIdx.y;
    const int P0  = blockIdx.x * 32;

    {   int c = tid >> 2, g = tid & 3;
        const float* src = &x[(size_t)c * HW + P0 + g * 8];
        float4 v0 = *(const float4*)src;
        float4 v1 = *(const float4*)(src + 4);
        *(float4*)&xs[c][g * 8]     = v0;
        *(float4*)&xs[c][g * 8 + 4] = v1;
    }
    {   int m = tid >> 3, c8 = (tid & 7) * 8;
        size_t row = (size_t)(m * HEADS + h) * CIN + c8;
        float4 a0 = *(const float4*)&Wq[row], a1 = *(const float4*)&Wq[row + 4];
        float4 b0 = *(const float4*)&Wk[row], b1 = *(const float4*)&Wk[row + 4];
        float4 c0 = *(const float4*)&Wv[row], c1 = *(const float4*)&Wv[row + 4];
        #pragma unroll
        for (int i = 0; i < 4; ++i) {
            Wlq[c8 + i][m]     = ((const float*)&a0)[i];
            Wlq[c8 + 4 + i][m] = ((const float*)&a1)[i];
            Wlk[c8 + i][m]     = ((const float*)&b0)[i];
            Wlk[c8 + 4 + i][m] = ((const float*)&b1)[i];
            Wlv[c8 + i][m]     = ((const float*)&c0)[i];
            Wlv[c8 + 4 + i][m] = ((const float*)&c1)[i];
        }
    }
    __syncthreads();

    const int a  = tid & 15, pg = tid >> 4;
    const int m0 = a * 2,    p0 = pg * 2;
    const int d0 = m0 * HEADS + h, d1 = d0 + HEADS;

    float q00 = bq[d0], q01 = q00, q10 = bq[d1], q11 = q10;
    float k00 = bk[d0], k01 = k00, k10 = bk[d1], k11 = k10;
    float v00 = bv[d0], v01 = v00, v10 = bv[d1], v11 = v10;

    #pragma unroll 8
    for (int c = 0; c < CIN; ++c) {
        float x0 = xs[c][p0], x1 = xs[c][p0 + 1];
        float wq0 = Wlq[c][m0], wq1 = Wlq[c][m0 + 1];
        float wk0 = Wlk[c][m0], wk1 = Wlk[c][m0 + 1];
        float wv0 = Wlv[c][m0], wv1 = Wlv[c][m0 + 1];
        q00 += wq0 * x0; q01 += wq0 * x1; q10 += wq1 * x0; q11 += wq1 * x1;
        k00 += wk0 * x0; k01 += wk0 * x1; k10 += wk1 * x0; k11 += wk1 * x1;
        v00 += wv0 * x0; v01 += wv0 * x1; v10 += wv1 * x0; v11 += wv1 * x1;
    }

    size_t qk0 = (size_t)h * HW * MIDC + (size_t)(P0 + p0) * MIDC + m0;
    *(uint_t*)&qh[qk0]        = pkh(q00, q10);
    *(uint_t*)&qh[qk0 + MIDC] = pkh(q01, q11);
    *(uint_t*)&kh[qk0]        = pkh(k00, k10);
    *(uint_t*)&kh[qk0 + MIDC] = pkh(k01, k11);
    size_t vb0 = (size_t)(h * MIDC + m0) * HW + P0 + p0;
    *(uint_t*)&vh[vb0]      = pkh(v00, v01);
    *(uint_t*)&vh[vb0 + HW] = pkh(v10, v11);
}

// ---------------- Kernel 2: MFMA flash attention, QT=32, K-split x8 ----------
// grid (98, 8, 2): q-tile x head x key-half. 4 waves; wave w owns tile pairs
// within its half; half 1 wave 0 also does tile 48. Partial (O,l) out (linear:
// max-free softmax), merged in outproj.
__global__ __launch_bounds__(256, 4) void attn_kernel(
    const f16* __restrict__ qh, const f16* __restrict__ kh,
    const f16* __restrict__ vh,
    const float* __restrict__ rowt, const float* __restrict__ colt,
    float* __restrict__ ob0, float* __restrict__ ob1,
    float* __restrict__ lb)
{
    __shared__ f16   Qs[QT][MIDC];                  // 2 KB
    __shared__ float Rb[QT][57];                    // 7.3 KB
    __shared__ float Cb[QT][60];                    // 7.7 KB (16B-aligned rows)
    __shared__ __align__(16) char pool[18944];      // P[4][16][136] f16; merge alias
    f16* PlBase = (f16*)pool;

    const int tid   = threadIdx.x;
    const int wave  = tid >> 6, lane = tid & 63;
    const int h     = blockIdx.y;
    const int half  = blockIdx.z;
    const int qbase = blockIdx.x * QT;
    const float c1  = 0.125f * L2E;

    float* __restrict__ obp = half ? ob1 : ob0;

    const f16* Qh = qh + (size_t)h * HW * MIDC;
    const f16* Kh = kh + (size_t)h * HW * MIDC;
    const f16* Vh = vh + (size_t)h * MIDC * HW;

    if (tid < 128) {
        int r = tid >> 2, c = (tid & 3) * 8;
        *(uint4*)&Qs[r][c] = *(const uint4*)&Qh[(size_t)(qbase + r) * MIDC + c];
    }
    __syncthreads();

    {   // bias tables: thread owns one q, 7 kp entries; Q-row via 4 b128 reads
        int q = tid >> 3, sub = tid & 7;
        int qg = qbase + q, qi = qg / WDIM, qj = qg % WDIM;
        half8 qr0 = *(const half8*)&Qs[q][0];
        half8 qr1 = *(const half8*)&Qs[q][8];
        half8 qr2 = *(const half8*)&Qs[q][16];
        half8 qr3 = *(const half8*)&Qs[q][24];
        for (int kp = sub; kp < WDIM; kp += 8) {
            const float* rt = &rowt[(kp - qi + WDIM - 1) * 16];
            const float* ct = &colt[(kp - qj + WDIM - 1) * 16];
            float s = 0.f, s2 = 0.f;
            #pragma unroll
            for (int c = 0; c < 8; ++c) {
                s  += (float)qr0[c] * rt[c] + (float)qr1[c] * rt[8 + c];
                s2 += (float)qr2[c] * ct[c] + (float)qr3[c] * ct[8 + c];
            }
            Rb[q][kp] = s * c1;
            Cb[q][kp] = s2 * c1;
        }
    }
    __syncthreads();

    const int qL  = lane & 15;
    const int grp = lane >> 4;
    half8 qfrag[2];
    qfrag[0] = *(const half8*)&Qs[qL][grp * 8];
    qfrag[1] = *(const half8*)&Qs[16 + qL][grp * 8];

    float lacc[2] = {0.f, 0.f};
    f32x4 o[2][2];
    #pragma unroll
    for (int i = 0; i < 2; ++i) { o[i][0] = (f32x4){0,0,0,0}; o[i][1] = (f32x4){0,0,0,0}; }

    int ki_s[8], kj_s[8];
    #pragma unroll
    for (int s = 0; s < 8; ++s) {
        int key0 = half * 1536 + wave * 128 + s * 16 + grp * 4;
        ki_s[s] = key0 / WDIM;
        kj_s[s] = key0 % WDIM;                       // multiple of 4, <= 52
    }

    f16* Pw = PlBase + wave * (16 * 136);

    for (int j = 0; j < 3; ++j) {
        const int base = half * 1536 + 512 * j + 128 * wave;

        half8 kfr[8];
        #pragma unroll
        for (int s = 0; s < 8; ++s)
            kfr[s] = *(const half8*)&Kh[(size_t)(base + s*16 + qL) * MIDC + grp*8];
        half8 vfr[2][4];
        #pragma unroll
        for (int ch = 0; ch < 2; ++ch)
            #pragma unroll
            for (int kf2 = 0; kf2 < 4; ++kf2)
                vfr[ch][kf2] = *(const half8*)
                    &Vh[(size_t)(ch*16 + qL) * HW + base + kf2*32 + grp*8];

        #pragma unroll
        for (int hf = 0; hf < 2; ++hf) {
            const int qrow = hf * 16 + qL;
            f32x4 sc[8];
            #pragma unroll
            for (int s = 0; s < 8; ++s) {
                f32x4 z = {0.f,0.f,0.f,0.f};
                sc[s] = __builtin_amdgcn_mfma_f32_16x16x32_f16(kfr[s], qfrag[hf], z, 0,0,0);
            }
            #pragma unroll
            for (int s = 0; s < 8; ++s) {
                float rb = Rb[qrow][ki_s[s]];
                float4 cbv = *(const float4*)&Cb[qrow][kj_s[s]];
                float e0 = __builtin_amdgcn_exp2f(fmaf(sc[s][0], c1, rb + cbv.x));
                float e1 = __builtin_amdgcn_exp2f(fmaf(sc[s][1], c1, rb + cbv.y));
                float e2 = __builtin_amdgcn_exp2f(fmaf(sc[s][2], c1, rb + cbv.z));
                float e3 = __builtin_amdgcn_exp2f(fmaf(sc[s][3], c1, rb + cbv.w));
                lacc[hf] += (e0 + e1) + (e2 + e3);
                uint2 w2; w2.x = pkh(e0, e1); w2.y = pkh(e2, e3);
                *(uint2*)&Pw[qL * 136 + s * 16 + grp * 4] = w2;
            }
            #pragma unroll
            for (int kf2 = 0; kf2 < 4; ++kf2) {
                half8 pf = *(const half8*)&Pw[qL * 136 + kf2 * 32 + grp * 8];
                o[hf][0] = __builtin_amdgcn_mfma_f32_16x16x32_f16(vfr[0][kf2], pf, o[hf][0], 0,0,0);
                o[hf][1] = __builtin_amdgcn_mfma_f32_16x16x32_f16(vfr[1][kf2], pf, o[hf][1], 0,0,0);
            }
        }

        #pragma unroll
        for (int s = 0; s < 8; ++s) {                // advance keys by 512
            kj_s[s] += 8;
            if (kj_s[s] >= WDIM) { kj_s[s] -= WDIM; ki_s[s] += 10; }
            else                 { ki_s[s] += 9; }
        }
    }

    if (half == 1 && wave == 0) {      // tile 48: keys 3072..3135
        const int base = 3072;
        half8 kfr[4];
        #pragma unroll
        for (int s = 0; s < 4; ++s)
            kfr[s] = *(const half8*)&Kh[(size_t)(base + s*16 + qL) * MIDC + grp*8];
        half8 vfr[2][2];
        #pragma unroll
        for (int ch = 0; ch < 2; ++ch)
            #pragma unroll
            for (int kf2 = 0; kf2 < 2; ++kf2)
                vfr[ch][kf2] = *(const half8*)
                    &Vh[(size_t)(ch*16 + qL) * HW + base + kf2*32 + grp*8];
        #pragma unroll
        for (int hf = 0; hf < 2; ++hf) {
            const int qrow = hf * 16 + qL;
            f32x4 sc[4];
            #pragma unroll
            for (int s = 0; s < 4; ++s) {
                f32x4 z = {0.f,0.f,0.f,0.f};
                sc[s] = __builtin_amdgcn_mfma_f32_16x16x32_f16(kfr[s], qfrag[hf], z, 0,0,0);
            }
            #pragma unroll
            for (int s = 0; s < 4; ++s) {
                int key0 = base + s * 16 + grp * 4;
                int ki = key0 / WDIM, kj = key0 % WDIM;
                float rb = Rb[qrow][ki];
                float4 cbv = *(const float4*)&Cb[qrow][kj];
                float e0 = __builtin_amdgcn_exp2f(fmaf(sc[s][0], c1, rb + cbv.x));
                float e1 = __builtin_amdgcn_exp2f(fmaf(sc[s][1], c1, rb + cbv.y));
                float e2 = __builtin_amdgcn_exp2f(fmaf(sc[s][2], c1, rb + cbv.z));
                float e3 = __builtin_amdgcn_exp2f(fmaf(sc[s][3], c1, rb + cbv.w));
                lacc[hf] += (e0 + e1) + (e2 + e3);
                uint2 w2; w2.x = pkh(e0, e1); w2.y = pkh(e2, e3);
                *(uint2*)&Pw[qL * 136 + s * 16 + grp * 4] = w2;
            }
            #pragma unroll
            for (int kf2 = 0; kf2 < 2; ++kf2) {
                half8 pf = *(const half8*)&Pw[qL * 136 + kf2 * 32 + grp * 8];
                o[hf][0] = __builtin_amdgcn_mfma_f32_16x16x32_f16(vfr[0][kf2], pf, o[hf][0], 0,0,0);
                o[hf][1] = __builtin_amdgcn_mfma_f32_16x16x32_f16(vfr[1][kf2], pf, o[hf][1], 0,0,0);
            }
        }
    }

    #pragma unroll
    for (int hf = 0; hf < 2; ++hf) {
        lacc[hf] += __shfl_xor(lacc[hf], 16);
        lacc[hf] += __shfl_xor(lacc[hf], 32);
    }

    // merge 4 waves (plain sums), write PARTIAL O and l
    __syncthreads();
    float* MOb = (float*)pool;                   // [4][32][36]
    float* Ll  = MOb + 4 * 32 * 36;              // [4][32]
    #pragma unroll
    for (int hf = 0; hf < 2; ++hf) {
        int row = wave * 32 + hf * 16 + qL;
        *(f32x4*)&MOb[row * 36 + grp * 4]      = o[hf][0];
        *(f32x4*)&MOb[row * 36 + 16 + grp * 4] = o[hf][1];
        if (grp == 0) Ll[row] = lacc[hf];
    }
    __syncthreads();

    {
        int q = tid & 31, cseg = tid >> 5;       // cseg 0..7 -> 4 channels each
        int qg = qbase + q;
        #pragma unroll
        for (int i = 0; i < 4; ++i) {
            int ch = cseg * 4 + i;
            float acc = 0.f;
            #pragma unroll
            for (int w = 0; w < 4; ++w)
                acc += MOb[(w*32 + q) * 36 + ch];
            obp[(size_t)(ch * HEADS + h) * HW + qg] = acc;
        }
        if (cseg == 0) {
            float l = (Ll[q] + Ll[32+q]) + (Ll[64+q] + Ll[96+q]);
            lb[(size_t)(half * HEADS + h) * HW + qg] = l;
        }
    }
}

// ---------------- Kernel 3: output 1x1 conv via MFMA + partial merge ---------
// grid (196), 64 threads. Merges ob0+ob1, scales by 1/(l0+l1) per (head,pos).
__global__ __launch_bounds__(64) void outproj_kernel(
    const float* __restrict__ ob0, const float* __restrict__ ob1,
    const float* __restrict__ lb,
    const float* __restrict__ Wo, const float* __restrict__ bo,
    float* __restrict__ out)
{
    const int lane = threadIdx.x;
    const int qL = lane & 15, grp = lane >> 4;
    const int p = blockIdx.x * 16 + qL;

    float invl[8];
    #pragma unroll
    for (int hh = 0; hh < 8; ++hh)
        invl[hh] = 1.f / (lb[(size_t)hh * HW + p] + lb[(size_t)(8 + hh) * HW + p]);

    f32x4 acc[4];
    #pragma unroll
    for (int mt = 0; mt < 4; ++mt) acc[mt] = (f32x4){0,0,0,0};

    #pragma unroll
    for (int ks = 0; ks < 8; ++ks) {
        half8 bf;
        #pragma unroll
        for (int jj = 0; jj < 8; ++jj) {
            size_t idx = (size_t)(ks * 32 + grp * 8 + jj) * HW + p;
            bf[jj] = (f16)((ob0[idx] + ob1[idx]) * invl[jj]);  // row&7 == jj
        }
        #pragma unroll
        for (int mt = 0; mt < 4; ++mt) {
            const float* wrow = &Wo[(size_t)(mt * 16 + qL) * DTOT + ks * 32 + grp * 8];
            float4 a0 = *(const float4*)wrow;
            float4 a1 = *(const float4*)(wrow + 4);
            half8 af;
            af[0] = (f16)a0.x; af[1] = (f16)a0.y; af[2] = (f16)a0.z; af[3] = (f16)a0.w;
            af[4] = (f16)a1.x; af[5] = (f16)a1.y; af[6] = (f16)a1.z; af[7] = (f16)a1.w;
            acc[mt] = __builtin_amdgcn_mfma_f32_16x16x32_f16(af, bf, acc[mt], 0, 0, 0);
        }
    }

    #pragma unroll
    for (int mt = 0; mt < 4; ++mt)
        #pragma unroll
        for (int r = 0; r < 4; ++r) {
            int d = mt * 16 + grp * 4 + r;
            out[(size_t)d * HW + p] = acc[mt][r] + bo[d];
        }
}

extern "C" void kernel_launch(void* const* d_in, const int* in_sizes, int n_in,
                              void* d_out, int out_size, void* d_ws, size_t ws_size,
                              hipStream_t stream)
{
    const float* x    = (const float*)d_in[0];
    const float* Wq   = (const float*)d_in[1];
    const float* bq   = (const float*)d_in[2];
    const float* Wk   = (const float*)d_in[3];
    const float* bk   = (const float*)d_in[4];
    const float* Wv   = (const float*)d_in[5];
    const float* bv   = (const float*)d_in[6];
    const float* Wo   = (const float*)d_in[7];
    const float* bo   = (const float*)d_in[8];
    const float* rowt = (const float*)d_in[9];
    const float* colt = (const float*)d_in[10];
    float* out = (float*)d_out;

    const size_t N = (size_t)DTOT * HW;
    f16* qh = (f16*)d_ws;                        // [h][pos][32]
    f16* kh = qh + N;
    f16* vh = kh + N;                            // [h*32+m][pos]
    float* ob0 = (float*)(vh + N);               // partial O, half 0
    float* ob1 = ob0 + N;                        // partial O, half 1
    float* lb  = ob1 + N;                        // [2][8][HW] partial l

    qkv_fused_kernel<<<dim3(HW / 32, HEADS), 256, 0, stream>>>(
        x, Wq, bq, Wk, bk, Wv, bv, qh, kh, vh);
    attn_kernel<<<dim3(HW / QT, HEADS, 2), 256, 0, stream>>>(
        qh, kh, vh, rowt, colt, ob0, ob1, lb);
    outproj_kernel<<<dim3(HW / 16), 64, 0, stream>>>(ob0, ob1, lb, Wo, bo, out);
}

// Round 11
// 163.937 us; speedup vs baseline: 1.2849x; 1.2849x over previous
//
#include <hip/hip_runtime.h>

#define HW    3136
#define CIN   64
#define MIDC  32
#define HEADS 8
#define DTOT  256
#define COUTC 64
#define WDIM  56
#define QT    32
#define L2E   1.4426950408889634f

typedef unsigned int uint_t;
typedef _Float16 f16;
typedef __attribute__((ext_vector_type(8))) _Float16 half8;
typedef __attribute__((ext_vector_type(2))) __fp16  fp16x2;
typedef __attribute__((ext_vector_type(4))) float f32x4;

union HU { fp16x2 h; uint_t u; };
__device__ __forceinline__ uint_t pkh(float a, float b) {
    HU u; u.h = __builtin_amdgcn_cvt_pkrtz(a, b); return u.u;
}

// ---------------- Kernel 1: fused QKV conv + layout (fp32 in -> f16 ws) ------
__global__ __launch_bounds__(256) void qkv_fused_kernel(
    const float* __restrict__ x,
    const float* __restrict__ Wq, const float* __restrict__ bq,
    const float* __restrict__ Wk, const float* __restrict__ bk,
    const float* __restrict__ Wv, const float* __restrict__ bv,
    f16* __restrict__ qh, f16* __restrict__ kh, f16* __restrict__ vh)
{
    __shared__ float xs[64][36];
    __shared__ float Wlq[64][34];
    __shared__ float Wlk[64][34];
    __shared__ float Wlv[64][34];

    const int tid = threadIdx.x;
    const int h   = blockIdx.y;
    const int P0  = blockIdx.x * 32;

    {   int c = tid >> 2, g = tid & 3;
        const float* src = &x[(size_t)c * HW + P0 + g * 8];
        float4 v0 = *(const float4*)src;
        float4 v1 = *(const float4*)(src + 4);
        *(float4*)&xs[c][g * 8]     = v0;
        *(float4*)&xs[c][g * 8 + 4] = v1;
    }
    {   int m = tid >> 3, c8 = (tid & 7) * 8;
        size_t row = (size_t)(m * HEADS + h) * CIN + c8;
        float4 a0 = *(const float4*)&Wq[row], a1 = *(const float4*)&Wq[row + 4];
        float4 b0 = *(const float4*)&Wk[row], b1 = *(const float4*)&Wk[row + 4];
        float4 c0 = *(const float4*)&Wv[row], c1 = *(const float4*)&Wv[row + 4];
        #pragma unroll
        for (int i = 0; i < 4; ++i) {
            Wlq[c8 + i][m]     = ((const float*)&a0)[i];
            Wlq[c8 + 4 + i][m] = ((const float*)&a1)[i];
            Wlk[c8 + i][m]     = ((const float*)&b0)[i];
            Wlk[c8 + 4 + i][m] = ((const float*)&b1)[i];
            Wlv[c8 + i][m]     = ((const float*)&c0)[i];
            Wlv[c8 + 4 + i][m] = ((const float*)&c1)[i];
        }
    }
    __syncthreads();

    const int a  = tid & 15, pg = tid >> 4;
    const int m0 = a * 2,    p0 = pg * 2;
    const int d0 = m0 * HEADS + h, d1 = d0 + HEADS;

    float q00 = bq[d0], q01 = q00, q10 = bq[d1], q11 = q10;
    float k00 = bk[d0], k01 = k00, k10 = bk[d1], k11 = k10;
    float v00 = bv[d0], v01 = v00, v10 = bv[d1], v11 = v10;

    #pragma unroll 8
    for (int c = 0; c < CIN; ++c) {
        float x0 = xs[c][p0], x1 = xs[c][p0 + 1];
        float wq0 = Wlq[c][m0], wq1 = Wlq[c][m0 + 1];
        float wk0 = Wlk[c][m0], wk1 = Wlk[c][m0 + 1];
        float wv0 = Wlv[c][m0], wv1 = Wlv[c][m0 + 1];
        q00 += wq0 * x0; q01 += wq0 * x1; q10 += wq1 * x0; q11 += wq1 * x1;
        k00 += wk0 * x0; k01 += wk0 * x1; k10 += wk1 * x0; k11 += wk1 * x1;
        v00 += wv0 * x0; v01 += wv0 * x1; v10 += wv1 * x0; v11 += wv1 * x1;
    }

    size_t qk0 = (size_t)h * HW * MIDC + (size_t)(P0 + p0) * MIDC + m0;
    *(uint_t*)&qh[qk0]        = pkh(q00, q10);
    *(uint_t*)&qh[qk0 + MIDC] = pkh(q01, q11);
    *(uint_t*)&kh[qk0]        = pkh(k00, k10);
    *(uint_t*)&kh[qk0 + MIDC] = pkh(k01, k11);
    size_t vb0 = (size_t)(h * MIDC + m0) * HW + P0 + p0;
    *(uint_t*)&vh[vb0]      = pkh(v00, v01);
    *(uint_t*)&vh[vb0 + HW] = pkh(v10, v11);
}

// ---------------- Kernel 2: MFMA flash attention, QT=32, K-split x2 blocks ---
// grid (98, 8, 2): q-tile x head x key-half. 4 waves; wave w owns tile pairs
// within its half; half 1 wave 0 also does tile 48. Partial (O,l) out (linear:
// max-free softmax), merged in outproj.
// NOTE: __launch_bounds__(256,3) — (256,4) caps regs at 128/lane and the
// compiler spills kfr/vfr to scratch: round-10 showed 400 MB HBM spill traffic.
__global__ __launch_bounds__(256, 3) void attn_kernel(
    const f16* __restrict__ qh, const f16* __restrict__ kh,
    const f16* __restrict__ vh,
    const float* __restrict__ rowt, const float* __restrict__ colt,
    float* __restrict__ ob0, float* __restrict__ ob1,
    float* __restrict__ lb)
{
    __shared__ f16   Qs[QT][MIDC];                  // 2 KB
    __shared__ float Rb[QT][57];                    // 7.3 KB
    __shared__ float Cb[QT][60];                    // 7.7 KB (16B-aligned rows)
    __shared__ __align__(16) char pool[18944];      // P[4][16][136] f16; merge alias
    f16* PlBase = (f16*)pool;

    const int tid   = threadIdx.x;
    const int wave  = tid >> 6, lane = tid & 63;
    const int h     = blockIdx.y;
    const int half  = blockIdx.z;
    const int qbase = blockIdx.x * QT;
    const float c1  = 0.125f * L2E;

    float* __restrict__ obp = half ? ob1 : ob0;

    const f16* Qh = qh + (size_t)h * HW * MIDC;
    const f16* Kh = kh + (size_t)h * HW * MIDC;
    const f16* Vh = vh + (size_t)h * MIDC * HW;

    if (tid < 128) {
        int r = tid >> 2, c = (tid & 3) * 8;
        *(uint4*)&Qs[r][c] = *(const uint4*)&Qh[(size_t)(qbase + r) * MIDC + c];
    }
    __syncthreads();

    {   // bias tables: thread owns one q, 7 kp entries; Q-row via 4 b128 reads
        int q = tid >> 3, sub = tid & 7;
        int qg = qbase + q, qi = qg / WDIM, qj = qg % WDIM;
        half8 qr0 = *(const half8*)&Qs[q][0];
        half8 qr1 = *(const half8*)&Qs[q][8];
        half8 qr2 = *(const half8*)&Qs[q][16];
        half8 qr3 = *(const half8*)&Qs[q][24];
        for (int kp = sub; kp < WDIM; kp += 8) {
            const float* rt = &rowt[(kp - qi + WDIM - 1) * 16];
            const float* ct = &colt[(kp - qj + WDIM - 1) * 16];
            float s = 0.f, s2 = 0.f;
            #pragma unroll
            for (int c = 0; c < 8; ++c) {
                s  += (float)qr0[c] * rt[c] + (float)qr1[c] * rt[8 + c];
                s2 += (float)qr2[c] * ct[c] + (float)qr3[c] * ct[8 + c];
            }
            Rb[q][kp] = s * c1;
            Cb[q][kp] = s2 * c1;
        }
    }
    __syncthreads();

    const int qL  = lane & 15;
    const int grp = lane >> 4;
    half8 qfrag[2];
    qfrag[0] = *(const half8*)&Qs[qL][grp * 8];
    qfrag[1] = *(const half8*)&Qs[16 + qL][grp * 8];

    float lacc[2] = {0.f, 0.f};
    f32x4 o[2][2];
    #pragma unroll
    for (int i = 0; i < 2; ++i) { o[i][0] = (f32x4){0,0,0,0}; o[i][1] = (f32x4){0,0,0,0}; }

    int ki_s[8], kj_s[8];
    #pragma unroll
    for (int s = 0; s < 8; ++s) {
        int key0 = half * 1536 + wave * 128 + s * 16 + grp * 4;
        ki_s[s] = key0 / WDIM;
        kj_s[s] = key0 % WDIM;                       // multiple of 4, <= 52
    }

    f16* Pw = PlBase + wave * (16 * 136);

    for (int j = 0; j < 3; ++j) {
        const int base = half * 1536 + 512 * j + 128 * wave;

        half8 kfr[8];
        #pragma unroll
        for (int s = 0; s < 8; ++s)
            kfr[s] = *(const half8*)&Kh[(size_t)(base + s*16 + qL) * MIDC + grp*8];
        half8 vfr[2][4];
        #pragma unroll
        for (int ch = 0; ch < 2; ++ch)
            #pragma unroll
            for (int kf2 = 0; kf2 < 4; ++kf2)
                vfr[ch][kf2] = *(const half8*)
                    &Vh[(size_t)(ch*16 + qL) * HW + base + kf2*32 + grp*8];

        #pragma unroll
        for (int hf = 0; hf < 2; ++hf) {
            const int qrow = hf * 16 + qL;
            f32x4 sc[8];
            #pragma unroll
            for (int s = 0; s < 8; ++s) {
                f32x4 z = {0.f,0.f,0.f,0.f};
                sc[s] = __builtin_amdgcn_mfma_f32_16x16x32_f16(kfr[s], qfrag[hf], z, 0,0,0);
            }
            #pragma unroll
            for (int s = 0; s < 8; ++s) {
                float rb = Rb[qrow][ki_s[s]];
                float4 cbv = *(const float4*)&Cb[qrow][kj_s[s]];
                float e0 = __builtin_amdgcn_exp2f(fmaf(sc[s][0], c1, rb + cbv.x));
                float e1 = __builtin_amdgcn_exp2f(fmaf(sc[s][1], c1, rb + cbv.y));
                float e2 = __builtin_amdgcn_exp2f(fmaf(sc[s][2], c1, rb + cbv.z));
                float e3 = __builtin_amdgcn_exp2f(fmaf(sc[s][3], c1, rb + cbv.w));
                lacc[hf] += (e0 + e1) + (e2 + e3);
                uint2 w2; w2.x = pkh(e0, e1); w2.y = pkh(e2, e3);
                *(uint2*)&Pw[qL * 136 + s * 16 + grp * 4] = w2;
            }
            #pragma unroll
            for (int kf2 = 0; kf2 < 4; ++kf2) {
                half8 pf = *(const half8*)&Pw[qL * 136 + kf2 * 32 + grp * 8];
                o[hf][0] = __builtin_amdgcn_mfma_f32_16x16x32_f16(vfr[0][kf2], pf, o[hf][0], 0,0,0);
                o[hf][1] = __builtin_amdgcn_mfma_f32_16x16x32_f16(vfr[1][kf2], pf, o[hf][1], 0,0,0);
            }
        }

        #pragma unroll
        for (int s = 0; s < 8; ++s) {                // advance keys by 512
            kj_s[s] += 8;
            if (kj_s[s] >= WDIM) { kj_s[s] -= WDIM; ki_s[s] += 10; }
            else                 { ki_s[s] += 9; }
        }
    }

    if (half == 1 && wave == 0) {      // tile 48: keys 3072..3135
        const int base = 3072;
        half8 kfr[4];
        #pragma unroll
        for (int s = 0; s < 4; ++s)
            kfr[s] = *(const half8*)&Kh[(size_t)(base + s*16 + qL) * MIDC + grp*8];
        half8 vfr[2][2];
        #pragma unroll
        for (int ch = 0; ch < 2; ++ch)
            #pragma unroll
            for (int kf2 = 0; kf2 < 2; ++kf2)
                vfr[ch][kf2] = *(const half8*)
                    &Vh[(size_t)(ch*16 + qL) * HW + base + kf2*32 + grp*8];
        #pragma unroll
        for (int hf = 0; hf < 2; ++hf) {
            const int qrow = hf * 16 + qL;
            f32x4 sc[4];
            #pragma unroll
            for (int s = 0; s < 4; ++s) {
                f32x4 z = {0.f,0.f,0.f,0.f};
                sc[s] = __builtin_amdgcn_mfma_f32_16x16x32_f16(kfr[s], qfrag[hf], z, 0,0,0);
            }
            #pragma unroll
            for (int s = 0; s < 4; ++s) {
                int key0 = base + s * 16 + grp * 4;
                int ki = key0 / WDIM, kj = key0 % WDIM;
                float rb = Rb[qrow][ki];
                float4 cbv = *(const float4*)&Cb[qrow][kj];
                float e0 = __builtin_amdgcn_exp2f(fmaf(sc[s][0], c1, rb + cbv.x));
                float e1 = __builtin_amdgcn_exp2f(fmaf(sc[s][1], c1, rb + cbv.y));
                float e2 = __builtin_amdgcn_exp2f(fmaf(sc[s][2], c1, rb + cbv.z));
                float e3 = __builtin_amdgcn_exp2f(fmaf(sc[s][3], c1, rb + cbv.w));
                lacc[hf] += (e0 + e1) + (e2 + e3);
                uint2 w2; w2.x = pkh(e0, e1); w2.y = pkh(e2, e3);
                *(uint2*)&Pw[qL * 136 + s * 16 + grp * 4] = w2;
            }
            #pragma unroll
            for (int kf2 = 0; kf2 < 2; ++kf2) {
                half8 pf = *(const half8*)&Pw[qL * 136 + kf2 * 32 + grp * 8];
                o[hf][0] = __builtin_amdgcn_mfma_f32_16x16x32_f16(vfr[0][kf2], pf, o[hf][0], 0,0,0);
                o[hf][1] = __builtin_amdgcn_mfma_f32_16x16x32_f16(vfr[1][kf2], pf, o[hf][1], 0,0,0);
            }
        }
    }

    #pragma unroll
    for (int hf = 0; hf < 2; ++hf) {
        lacc[hf] += __shfl_xor(lacc[hf], 16);
        lacc[hf] += __shfl_xor(lacc[hf], 32);
    }

    // merge 4 waves (plain sums), write PARTIAL O and l
    __syncthreads();
    float* MOb = (float*)pool;                   // [4][32][36]
    float* Ll  = MOb + 4 * 32 * 36;              // [4][32]
    #pragma unroll
    for (int hf = 0; hf < 2; ++hf) {
        int row = wave * 32 + hf * 16 + qL;
        *(f32x4*)&MOb[row * 36 + grp * 4]      = o[hf][0];
        *(f32x4*)&MOb[row * 36 + 16 + grp * 4] = o[hf][1];
        if (grp == 0) Ll[row] = lacc[hf];
    }
    __syncthreads();

    {
        int q = tid & 31, cseg = tid >> 5;       // cseg 0..7 -> 4 channels each
        int qg = qbase + q;
        #pragma unroll
        for (int i = 0; i < 4; ++i) {
            int ch = cseg * 4 + i;
            float acc = 0.f;
            #pragma unroll
            for (int w = 0; w < 4; ++w)
                acc += MOb[(w*32 + q) * 36 + ch];
            obp[(size_t)(ch * HEADS + h) * HW + qg] = acc;
        }
        if (cseg == 0) {
            float l = (Ll[q] + Ll[32+q]) + (Ll[64+q] + Ll[96+q]);
            lb[(size_t)(half * HEADS + h) * HW + qg] = l;
        }
    }
}

// ---------------- Kernel 3: output 1x1 conv via MFMA + partial merge ---------
// grid (196), 64 threads. Merges ob0+ob1, scales by 1/(l0+l1) per (head,pos).
__global__ __launch_bounds__(64) void outproj_kernel(
    const float* __restrict__ ob0, const float* __restrict__ ob1,
    const float* __restrict__ lb,
    const float* __restrict__ Wo, const float* __restrict__ bo,
    float* __restrict__ out)
{
    const int lane = threadIdx.x;
    const int qL = lane & 15, grp = lane >> 4;
    const int p = blockIdx.x * 16 + qL;

    float invl[8];
    #pragma unroll
    for (int hh = 0; hh < 8; ++hh)
        invl[hh] = 1.f / (lb[(size_t)hh * HW + p] + lb[(size_t)(8 + hh) * HW + p]);

    f32x4 acc[4];
    #pragma unroll
    for (int mt = 0; mt < 4; ++mt) acc[mt] = (f32x4){0,0,0,0};

    #pragma unroll
    for (int ks = 0; ks < 8; ++ks) {
        half8 bf;
        #pragma unroll
        for (int jj = 0; jj < 8; ++jj) {
            size_t idx = (size_t)(ks * 32 + grp * 8 + jj) * HW + p;
            bf[jj] = (f16)((ob0[idx] + ob1[idx]) * invl[jj]);  // row&7 == jj
        }
        #pragma unroll
        for (int mt = 0; mt < 4; ++mt) {
            const float* wrow = &Wo[(size_t)(mt * 16 + qL) * DTOT + ks * 32 + grp * 8];
            float4 a0 = *(const float4*)wrow;
            float4 a1 = *(const float4*)(wrow + 4);
            half8 af;
            af[0] = (f16)a0.x; af[1] = (f16)a0.y; af[2] = (f16)a0.z; af[3] = (f16)a0.w;
            af[4] = (f16)a1.x; af[5] = (f16)a1.y; af[6] = (f16)a1.z; af[7] = (f16)a1.w;
            acc[mt] = __builtin_amdgcn_mfma_f32_16x16x32_f16(af, bf, acc[mt], 0, 0, 0);
        }
    }

    #pragma unroll
    for (int mt = 0; mt < 4; ++mt)
        #pragma unroll
        for (int r = 0; r < 4; ++r) {
            int d = mt * 16 + grp * 4 + r;
            out[(size_t)d * HW + p] = acc[mt][r] + bo[d];
        }
}

extern "C" void kernel_launch(void* const* d_in, const int* in_sizes, int n_in,
                              void* d_out, int out_size, void* d_ws, size_t ws_size,
                              hipStream_t stream)
{
    const float* x    = (const float*)d_in[0];
    const float* Wq   = (const float*)d_in[1];
    const float* bq   = (const float*)d_in[2];
    const float* Wk   = (const float*)d_in[3];
    const float* bk   = (const float*)d_in[4];
    const float* Wv   = (const float*)d_in[5];
    const float* bv   = (const float*)d_in[6];
    const float* Wo   = (const float*)d_in[7];
    const float* bo   = (const float*)d_in[8];
    const float* rowt = (const float*)d_in[9];
    const float* colt = (const float*)d_in[10];
    float* out = (float*)d_out;

    const size_t N = (size_t)DTOT * HW;
    f16* qh = (f16*)d_ws;                        // [h][pos][32]
    f16* kh = qh + N;
    f16* vh = kh + N;                            // [h*32+m][pos]
    float* ob0 = (float*)(vh + N);               // partial O, half 0
    float* ob1 = ob0 + N;                        // partial O, half 1
    float* lb  = ob1 + N;                        // [2][8][HW] partial l

    qkv_fused_kernel<<<dim3(HW / 32, HEADS), 256, 0, stream>>>(
        x, Wq, bq, Wk, bk, Wv, bv, qh, kh, vh);
    attn_kernel<<<dim3(HW / QT, HEADS, 2), 256, 0, stream>>>(
        qh, kh, vh, rowt, colt, ob0, ob1, lb);
    outproj_kernel<<<dim3(HW / 16), 64, 0, stream>>>(ob0, ob1, lb, Wo, bo, out);
}

// Round 12
// 149.491 us; speedup vs baseline: 1.4091x; 1.0966x over previous
//
#include <hip/hip_runtime.h>

#define HW    3136
#define CIN   64
#define MIDC  32
#define HEADS 8
#define DTOT  256
#define COUTC 64
#define WDIM  56
#define QT    32
#define L2E   1.4426950408889634f

typedef unsigned int uint_t;
typedef _Float16 f16;
typedef __attribute__((ext_vector_type(8))) _Float16 half8;
typedef __attribute__((ext_vector_type(2))) __fp16  fp16x2;
typedef __attribute__((ext_vector_type(4))) float f32x4;

union HU { fp16x2 h; uint_t u; };
__device__ __forceinline__ uint_t pkh(float a, float b) {
    HU u; u.h = __builtin_amdgcn_cvt_pkrtz(a, b); return u.u;
}

// ---------------- Kernel 1: fused QKV conv + layout (fp32 in -> f16 ws) ------
__global__ __launch_bounds__(256) void qkv_fused_kernel(
    const float* __restrict__ x,
    const float* __restrict__ Wq, const float* __restrict__ bq,
    const float* __restrict__ Wk, const float* __restrict__ bk,
    const float* __restrict__ Wv, const float* __restrict__ bv,
    f16* __restrict__ qh, f16* __restrict__ kh, f16* __restrict__ vh)
{
    __shared__ float xs[64][36];
    __shared__ float Wlq[64][34];
    __shared__ float Wlk[64][34];
    __shared__ float Wlv[64][34];

    const int tid = threadIdx.x;
    const int h   = blockIdx.y;
    const int P0  = blockIdx.x * 32;

    {   int c = tid >> 2, g = tid & 3;
        const float* src = &x[(size_t)c * HW + P0 + g * 8];
        float4 v0 = *(const float4*)src;
        float4 v1 = *(const float4*)(src + 4);
        *(float4*)&xs[c][g * 8]     = v0;
        *(float4*)&xs[c][g * 8 + 4] = v1;
    }
    {   int m = tid >> 3, c8 = (tid & 7) * 8;
        size_t row = (size_t)(m * HEADS + h) * CIN + c8;
        float4 a0 = *(const float4*)&Wq[row], a1 = *(const float4*)&Wq[row + 4];
        float4 b0 = *(const float4*)&Wk[row], b1 = *(const float4*)&Wk[row + 4];
        float4 c0 = *(const float4*)&Wv[row], c1 = *(const float4*)&Wv[row + 4];
        #pragma unroll
        for (int i = 0; i < 4; ++i) {
            Wlq[c8 + i][m]     = ((const float*)&a0)[i];
            Wlq[c8 + 4 + i][m] = ((const float*)&a1)[i];
            Wlk[c8 + i][m]     = ((const float*)&b0)[i];
            Wlk[c8 + 4 + i][m] = ((const float*)&b1)[i];
            Wlv[c8 + i][m]     = ((const float*)&c0)[i];
            Wlv[c8 + 4 + i][m] = ((const float*)&c1)[i];
        }
    }
    __syncthreads();

    const int a  = tid & 15, pg = tid >> 4;
    const int m0 = a * 2,    p0 = pg * 2;
    const int d0 = m0 * HEADS + h, d1 = d0 + HEADS;

    float q00 = bq[d0], q01 = q00, q10 = bq[d1], q11 = q10;
    float k00 = bk[d0], k01 = k00, k10 = bk[d1], k11 = k10;
    float v00 = bv[d0], v01 = v00, v10 = bv[d1], v11 = v10;

    #pragma unroll 8
    for (int c = 0; c < CIN; ++c) {
        float x0 = xs[c][p0], x1 = xs[c][p0 + 1];
        float wq0 = Wlq[c][m0], wq1 = Wlq[c][m0 + 1];
        float wk0 = Wlk[c][m0], wk1 = Wlk[c][m0 + 1];
        float wv0 = Wlv[c][m0], wv1 = Wlv[c][m0 + 1];
        q00 += wq0 * x0; q01 += wq0 * x1; q10 += wq1 * x0; q11 += wq1 * x1;
        k00 += wk0 * x0; k01 += wk0 * x1; k10 += wk1 * x0; k11 += wk1 * x1;
        v00 += wv0 * x0; v01 += wv0 * x1; v10 += wv1 * x0; v11 += wv1 * x1;
    }

    size_t qk0 = (size_t)h * HW * MIDC + (size_t)(P0 + p0) * MIDC + m0;
    *(uint_t*)&qh[qk0]        = pkh(q00, q10);
    *(uint_t*)&qh[qk0 + MIDC] = pkh(q01, q11);
    *(uint_t*)&kh[qk0]        = pkh(k00, k10);
    *(uint_t*)&kh[qk0 + MIDC] = pkh(k01, k11);
    size_t vb0 = (size_t)(h * MIDC + m0) * HW + P0 + p0;
    *(uint_t*)&vh[vb0]      = pkh(v00, v01);
    *(uint_t*)&vh[vb0 + HW] = pkh(v10, v11);
}

// ---------------- Kernel 2: MFMA flash attention, QT=32 (round-9 core) ------
// grid (98, 8), 4 waves, K-split by wave; wave 0 does tile 48.
// Epilogue: normalized O -> f16 obf[pos][cc], cc = h*32 + m.
// NOTE: (256,3) — (256,4) caps regs at 128/lane -> kfr/vfr spill (round 10:
// 400 MB HBM scratch traffic). Do not raise.
__global__ __launch_bounds__(256, 3) void attn_kernel(
    const f16* __restrict__ qh, const f16* __restrict__ kh,
    const f16* __restrict__ vh,
    const float* __restrict__ rowt, const float* __restrict__ colt,
    f16* __restrict__ obf)
{
    __shared__ f16   Qs[QT][MIDC];                  // 2 KB
    __shared__ float Rb[QT][57];                    // 7.3 KB
    __shared__ float Cb[QT][60];                    // 7.7 KB (16B-aligned rows)
    __shared__ __align__(16) char pool[18944];      // P[4][16][136] f16; merge alias
    f16* PlBase = (f16*)pool;

    const int tid   = threadIdx.x;
    const int wave  = tid >> 6, lane = tid & 63;
    const int h     = blockIdx.y;
    const int qbase = blockIdx.x * QT;
    const float c1  = 0.125f * L2E;

    const f16* Qh = qh + (size_t)h * HW * MIDC;
    const f16* Kh = kh + (size_t)h * HW * MIDC;
    const f16* Vh = vh + (size_t)h * MIDC * HW;

    if (tid < 128) {
        int r = tid >> 2, c = (tid & 3) * 8;
        *(uint4*)&Qs[r][c] = *(const uint4*)&Qh[(size_t)(qbase + r) * MIDC + c];
    }
    __syncthreads();

    {   // bias tables: thread owns one q, 7 kp entries; Q-row via 4 b128 reads
        int q = tid >> 3, sub = tid & 7;
        int qg = qbase + q, qi = qg / WDIM, qj = qg % WDIM;
        half8 qr0 = *(const half8*)&Qs[q][0];
        half8 qr1 = *(const half8*)&Qs[q][8];
        half8 qr2 = *(const half8*)&Qs[q][16];
        half8 qr3 = *(const half8*)&Qs[q][24];
        for (int kp = sub; kp < WDIM; kp += 8) {
            const float* rt = &rowt[(kp - qi + WDIM - 1) * 16];
            const float* ct = &colt[(kp - qj + WDIM - 1) * 16];
            float s = 0.f, s2 = 0.f;
            #pragma unroll
            for (int c = 0; c < 8; ++c) {
                s  += (float)qr0[c] * rt[c] + (float)qr1[c] * rt[8 + c];
                s2 += (float)qr2[c] * ct[c] + (float)qr3[c] * ct[8 + c];
            }
            Rb[q][kp] = s * c1;
            Cb[q][kp] = s2 * c1;
        }
    }
    __syncthreads();

    const int qL  = lane & 15;
    const int grp = lane >> 4;
    half8 qfrag[2];
    qfrag[0] = *(const half8*)&Qs[qL][grp * 8];
    qfrag[1] = *(const half8*)&Qs[16 + qL][grp * 8];

    float lacc[2] = {0.f, 0.f};
    f32x4 o[2][2];
    #pragma unroll
    for (int i = 0; i < 2; ++i) { o[i][0] = (f32x4){0,0,0,0}; o[i][1] = (f32x4){0,0,0,0}; }

    int ki_s[8], kj_s[8];
    #pragma unroll
    for (int s = 0; s < 8; ++s) {
        int key0 = wave * 128 + s * 16 + grp * 4;
        ki_s[s] = key0 / WDIM;
        kj_s[s] = key0 % WDIM;                       // multiple of 4, <= 52
    }

    f16* Pw = PlBase + wave * (16 * 136);

    for (int j = 0; j < 6; ++j) {
        const int base = 512 * j + 128 * wave;

        half8 kfr[8];
        #pragma unroll
        for (int s = 0; s < 8; ++s)
            kfr[s] = *(const half8*)&Kh[(size_t)(base + s*16 + qL) * MIDC + grp*8];
        half8 vfr[2][4];
        #pragma unroll
        for (int ch = 0; ch < 2; ++ch)
            #pragma unroll
            for (int kf2 = 0; kf2 < 4; ++kf2)
                vfr[ch][kf2] = *(const half8*)
                    &Vh[(size_t)(ch*16 + qL) * HW + base + kf2*32 + grp*8];

        #pragma unroll
        for (int hf = 0; hf < 2; ++hf) {
            const int qrow = hf * 16 + qL;
            f32x4 sc[8];
            #pragma unroll
            for (int s = 0; s < 8; ++s) {
                f32x4 z = {0.f,0.f,0.f,0.f};
                sc[s] = __builtin_amdgcn_mfma_f32_16x16x32_f16(kfr[s], qfrag[hf], z, 0,0,0);
            }
            #pragma unroll
            for (int s = 0; s < 8; ++s) {
                float rb = Rb[qrow][ki_s[s]];
                float4 cbv = *(const float4*)&Cb[qrow][kj_s[s]];
                float e0 = __builtin_amdgcn_exp2f(fmaf(sc[s][0], c1, rb + cbv.x));
                float e1 = __builtin_amdgcn_exp2f(fmaf(sc[s][1], c1, rb + cbv.y));
                float e2 = __builtin_amdgcn_exp2f(fmaf(sc[s][2], c1, rb + cbv.z));
                float e3 = __builtin_amdgcn_exp2f(fmaf(sc[s][3], c1, rb + cbv.w));
                lacc[hf] += (e0 + e1) + (e2 + e3);
                uint2 w2; w2.x = pkh(e0, e1); w2.y = pkh(e2, e3);
                *(uint2*)&Pw[qL * 136 + s * 16 + grp * 4] = w2;
            }
            #pragma unroll
            for (int kf2 = 0; kf2 < 4; ++kf2) {
                half8 pf = *(const half8*)&Pw[qL * 136 + kf2 * 32 + grp * 8];
                o[hf][0] = __builtin_amdgcn_mfma_f32_16x16x32_f16(vfr[0][kf2], pf, o[hf][0], 0,0,0);
                o[hf][1] = __builtin_amdgcn_mfma_f32_16x16x32_f16(vfr[1][kf2], pf, o[hf][1], 0,0,0);
            }
        }

        #pragma unroll
        for (int s = 0; s < 8; ++s) {                // advance keys by 512
            kj_s[s] += 8;
            if (kj_s[s] >= WDIM) { kj_s[s] -= WDIM; ki_s[s] += 10; }
            else                 { ki_s[s] += 9; }
        }
    }

    if (wave == 0) {       // tile 48: keys 3072..3135
        const int base = 3072;
        half8 kfr[4];
        #pragma unroll
        for (int s = 0; s < 4; ++s)
            kfr[s] = *(const half8*)&Kh[(size_t)(base + s*16 + qL) * MIDC + grp*8];
        half8 vfr[2][2];
        #pragma unroll
        for (int ch = 0; ch < 2; ++ch)
            #pragma unroll
            for (int kf2 = 0; kf2 < 2; ++kf2)
                vfr[ch][kf2] = *(const half8*)
                    &Vh[(size_t)(ch*16 + qL) * HW + base + kf2*32 + grp*8];
        #pragma unroll
        for (int hf = 0; hf < 2; ++hf) {
            const int qrow = hf * 16 + qL;
            f32x4 sc[4];
            #pragma unroll
            for (int s = 0; s < 4; ++s) {
                f32x4 z = {0.f,0.f,0.f,0.f};
                sc[s] = __builtin_amdgcn_mfma_f32_16x16x32_f16(kfr[s], qfrag[hf], z, 0,0,0);
            }
            #pragma unroll
            for (int s = 0; s < 4; ++s) {
                int key0 = base + s * 16 + grp * 4;
                int ki = key0 / WDIM, kj = key0 % WDIM;
                float rb = Rb[qrow][ki];
                float4 cbv = *(const float4*)&Cb[qrow][kj];
                float e0 = __builtin_amdgcn_exp2f(fmaf(sc[s][0], c1, rb + cbv.x));
                float e1 = __builtin_amdgcn_exp2f(fmaf(sc[s][1], c1, rb + cbv.y));
                float e2 = __builtin_amdgcn_exp2f(fmaf(sc[s][2], c1, rb + cbv.z));
                float e3 = __builtin_amdgcn_exp2f(fmaf(sc[s][3], c1, rb + cbv.w));
                lacc[hf] += (e0 + e1) + (e2 + e3);
                uint2 w2; w2.x = pkh(e0, e1); w2.y = pkh(e2, e3);
                *(uint2*)&Pw[qL * 136 + s * 16 + grp * 4] = w2;
            }
            #pragma unroll
            for (int kf2 = 0; kf2 < 2; ++kf2) {
                half8 pf = *(const half8*)&Pw[qL * 136 + kf2 * 32 + grp * 8];
                o[hf][0] = __builtin_amdgcn_mfma_f32_16x16x32_f16(vfr[0][kf2], pf, o[hf][0], 0,0,0);
                o[hf][1] = __builtin_amdgcn_mfma_f32_16x16x32_f16(vfr[1][kf2], pf, o[hf][1], 0,0,0);
            }
        }
    }

    #pragma unroll
    for (int hf = 0; hf < 2; ++hf) {
        lacc[hf] += __shfl_xor(lacc[hf], 16);
        lacc[hf] += __shfl_xor(lacc[hf], 32);
    }

    // merge 4 waves (plain sums), normalize, write f16 obf[pos][cc=h*32+m]
    __syncthreads();
    float* MOb = (float*)pool;                   // [4][32][36]
    float* Ll  = MOb + 4 * 32 * 36;              // [4][32]
    #pragma unroll
    for (int hf = 0; hf < 2; ++hf) {
        int row = wave * 32 + hf * 16 + qL;
        *(f32x4*)&MOb[row * 36 + grp * 4]      = o[hf][0];
        *(f32x4*)&MOb[row * 36 + 16 + grp * 4] = o[hf][1];
        if (grp == 0) Ll[row] = lacc[hf];
    }
    __syncthreads();

    {
        int q = tid & 31, cseg = tid >> 5;       // cseg 0..7 -> 4 channels each
        float l = (Ll[q] + Ll[32+q]) + (Ll[64+q] + Ll[96+q]);
        float invl = 1.f / l;
        int qg = qbase + q;
        float a0 = 0.f, a1 = 0.f, a2 = 0.f, a3 = 0.f;
        #pragma unroll
        for (int w = 0; w < 4; ++w) {
            const float* r = &MOb[(w*32 + q) * 36 + cseg * 4];
            a0 += r[0]; a1 += r[1]; a2 += r[2]; a3 += r[3];
        }
        uint2 pk;
        pk.x = pkh(a0 * invl, a1 * invl);
        pk.y = pkh(a2 * invl, a3 * invl);
        *(uint2*)&obf[(size_t)qg * DTOT + h * MIDC + cseg * 4] = pk;
    }
}

// ---------------- Kernel 3: output 1x1 conv via MFMA, LDS-staged Wo ----------
// grid (49), 256 thr = 4 waves; block covers 64 positions x 64 out-ch.
// obf layout [pos][cc], cc = h*32+m  <->  Wo column (m*8+h), permuted at stage.
__global__ __launch_bounds__(256) void outproj_kernel(
    const f16* __restrict__ obf, const float* __restrict__ Wo,
    const float* __restrict__ bo, float* __restrict__ out)
{
    __shared__ f16  WoL[64][264];                // [d][cc] f16, pad 264 (33 KB)
    __shared__ float bol[64];

    const int tid = threadIdx.x;
    {
        int d = tid >> 2, part = tid & 3;
        const float* wr = &Wo[(size_t)d * DTOT];
        #pragma unroll
        for (int i = 0; i < 32; ++i) {
            int cc = part * 64 + i * 2;          // cc, cc+1 share h for even cc
            int h0 = cc >> 5, m0 = cc & 31;
            float w0 = wr[m0 * 8 + h0];
            float w1 = wr[(m0 + 1) * 8 + h0];    // cc+1: same h, m+1 (m0<31 even)
            *(uint_t*)&WoL[d][cc] = pkh(w0, w1);
        }
        if (tid < 64) bol[tid] = bo[tid];
    }
    __syncthreads();

    const int wave = tid >> 6, lane = tid & 63;
    const int qL = lane & 15, grp = lane >> 4;
    const int p = blockIdx.x * 64 + wave * 16 + qL;

    f32x4 acc[4];
    #pragma unroll
    for (int mt = 0; mt < 4; ++mt) acc[mt] = (f32x4){0,0,0,0};

    #pragma unroll
    for (int ks = 0; ks < 8; ++ks) {
        half8 bf = *(const half8*)&obf[(size_t)p * DTOT + ks * 32 + grp * 8];
        #pragma unroll
        for (int mt = 0; mt < 4; ++mt) {
            half8 af = *(const half8*)&WoL[mt * 16 + qL][ks * 32 + grp * 8];
            acc[mt] = __builtin_amdgcn_mfma_f32_16x16x32_f16(af, bf, acc[mt], 0, 0, 0);
        }
    }

    #pragma unroll
    for (int mt = 0; mt < 4; ++mt)
        #pragma unroll
        for (int r = 0; r < 4; ++r) {
            int d = mt * 16 + grp * 4 + r;
            out[(size_t)d * HW + p] = acc[mt][r] + bol[d];
        }
}

extern "C" void kernel_launch(void* const* d_in, const int* in_sizes, int n_in,
                              void* d_out, int out_size, void* d_ws, size_t ws_size,
                              hipStream_t stream)
{
    const float* x    = (const float*)d_in[0];
    const float* Wq   = (const float*)d_in[1];
    const float* bq   = (const float*)d_in[2];
    const float* Wk   = (const float*)d_in[3];
    const float* bk   = (const float*)d_in[4];
    const float* Wv   = (const float*)d_in[5];
    const float* bv   = (const float*)d_in[6];
    const float* Wo   = (const float*)d_in[7];
    const float* bo   = (const float*)d_in[8];
    const float* rowt = (const float*)d_in[9];
    const float* colt = (const float*)d_in[10];
    float* out = (float*)d_out;

    const size_t N = (size_t)DTOT * HW;
    f16* qh  = (f16*)d_ws;                       // [h][pos][32]
    f16* kh  = qh + N;
    f16* vh  = kh + N;                           // [h*32+m][pos]
    f16* obf = vh + N;                           // [pos][256] f16 normalized O

    qkv_fused_kernel<<<dim3(HW / 32, HEADS), 256, 0, stream>>>(
        x, Wq, bq, Wk, bk, Wv, bv, qh, kh, vh);
    attn_kernel<<<dim3(HW / QT, HEADS), 256, 0, stream>>>(
        qh, kh, vh, rowt, colt, obf);
    outproj_kernel<<<dim3(HW / 64), 256, 0, stream>>>(obf, Wo, bo, out);
}